// Round 4
// baseline (1076.924 us; speedup 1.0000x reference)
//
#include <hip/hip_runtime.h>
#include <hip/hip_bf16.h>

// ---------------------------------------------------------------------------
// TAGConv (K=2) x2 + segment-max pool + linear head. bf16 intermediates,
// fp32 accumulate, int8 row-quantized gathers for ALL props. Layer-2
// commuted: z2@W2 = X1@W2a + P(X1@W2b + P(X1@W2c)). CSR via counting sort.
// Round 13: prop8 pinned at ~116us / 364MB fetch across 3 structural
// variants -> at its traffic roofline. Attack the hidden 680us instead:
// (a) QMODE GEMM epilogue writes biased-u8 + per-32col scales directly
//     (kills both quant_bf16_256 dispatches, shrinks 2 GEMM writes 51->29MB;
//     finer scale groups than per-row -> accuracy same or better);
// (b) XCD-chunked swizzle + y-fastest block decode on all GEMMs so the 4
//     col-blocks sharing an A-panel run adjacently on one XCD (A read ~1x
//     not 4x per L2).
// ---------------------------------------------------------------------------

typedef unsigned short u16;
typedef unsigned int u32;
typedef unsigned char u8;

__device__ inline float u2f(u16 u) { return __uint_as_float(((u32)u) << 16); }
__device__ inline u16 f2u(float f) {
    __hip_bfloat16 b = __float2bfloat16(f);
    return *reinterpret_cast<u16*>(&b);
}

// ---------------------- CSR build: counting sort ---------------------------
// NPB = 128 nodes per bucket, NC = 128 edge chunks. NB = ceil(N/NPB) <= 784.

constexpr int NPB = 128, NC = 128, NBMAX = 784;

__global__ __launch_bounds__(256) void countA_kernel(
    const int* __restrict__ dst, int* __restrict__ Hmat, int E, int CS, int NB) {
    __shared__ int hist[NBMAX];
    int tid = threadIdx.x;
    for (int b = tid; b < NB; b += 256) hist[b] = 0;
    __syncthreads();
    int base = blockIdx.x * CS;
    int end = base + CS < E ? base + CS : E;
    for (int i = base + tid; i < end; i += 256) {
        int d = __builtin_nontemporal_load(dst + i);
        atomicAdd(&hist[d >> 7], 1);
    }
    __syncthreads();
    for (int b = tid; b < NB; b += 256) Hmat[b * NC + blockIdx.x] = hist[b];
}

__global__ __launch_bounds__(256) void scatterC_kernel(
    const int* __restrict__ src, const int* __restrict__ dst,
    const int* __restrict__ Omat, uint2* __restrict__ Earr,
    int E, int CS, int NB) {
    __shared__ int cur[NBMAX];
    int tid = threadIdx.x;
    int c = blockIdx.x;
    for (int b = tid; b < NB; b += 256) cur[b] = Omat[b * NC + c];
    __syncthreads();
    int base = c * CS;
    int end = base + CS < E ? base + CS : E;
    for (int i = base + tid; i < end; i += 256) {
        int d = __builtin_nontemporal_load(dst + i);
        int s = __builtin_nontemporal_load(src + i);
        int pos = atomicAdd(&cur[d >> 7], 1);
        uint2 e;
        e.x = (u32)s;
        e.y = (u32)(d & (NPB - 1));
        Earr[pos] = e;
    }
}

// One block per bucket: local deg count -> rowptr/normv, then colidx scatter.
__global__ __launch_bounds__(256) void fineD_kernel(
    const uint2* __restrict__ Earr, const int* __restrict__ Omat,
    int* __restrict__ colidx, int* __restrict__ rowptr,
    float* __restrict__ normv, int N, int E, int NB) {
    __shared__ int cnt[NPB];
    __shared__ int scn[NPB];
    __shared__ int cur2[NPB];
    int tid = threadIdx.x;
    int b = blockIdx.x;
    int base = Omat[b * NC];
    int end = Omat[(b + 1) * NC];   // Omat[NB*NC] = E (scan tail)
    if (tid < NPB) cnt[tid] = 0;
    __syncthreads();
    for (int i = base + tid; i < end; i += 256)
        atomicAdd(&cnt[Earr[i].y], 1);
    __syncthreads();
    if (tid < NPB) scn[tid] = cnt[tid];
    __syncthreads();
    for (int off = 1; off < NPB; off <<= 1) {
        int v = (tid < NPB && tid >= off) ? scn[tid - off] : 0;
        __syncthreads();
        if (tid < NPB) scn[tid] += v;
        __syncthreads();
    }
    int node0 = b * NPB;
    if (tid < NPB) {
        int excl = scn[tid] - cnt[tid];
        cur2[tid] = base + excl;
        int node = node0 + tid;
        if (node < N) {
            rowptr[node] = base + excl;
            int d = cnt[tid];
            float fd = d < 1 ? 1.0f : (float)d;
            normv[node] = rsqrtf(fd);
        }
    }
    if (b == 0 && tid == 0) rowptr[N] = E;
    __syncthreads();
    for (int i = base + tid; i < end; i += 256) {
        uint2 e = Earr[i];
        int pos = atomicAdd(&cur2[e.y], 1);
        colidx[pos] = (int)e.x;
    }
}

// Multi-block scan.
__global__ void scan1_kernel(const int* __restrict__ in, int* __restrict__ outp,
                             int* __restrict__ bsum, int n) {
    __shared__ int sd[1024];
    int t = threadIdx.x;
    int i = blockIdx.x * 1024 + t;
    int v = (i < n) ? in[i] : 0;
    sd[t] = v;
    __syncthreads();
    for (int off = 1; off < 1024; off <<= 1) {
        int x = (t >= off) ? sd[t - off] : 0;
        __syncthreads();
        sd[t] += x;
        __syncthreads();
    }
    if (i < n) outp[i] = sd[t] - v;
    if (t == 1023) bsum[blockIdx.x] = sd[t];
}

__global__ void scan2_kernel(int* __restrict__ bsum, int nb) {
    __shared__ int sd[1024];
    int t = threadIdx.x;
    int v = (t < nb) ? bsum[t] : 0;
    sd[t] = v;
    __syncthreads();
    for (int off = 1; off < 1024; off <<= 1) {
        int x = (t >= off) ? sd[t - off] : 0;
        __syncthreads();
        sd[t] += x;
        __syncthreads();
    }
    if (t < nb) bsum[t] = sd[t] - v;
}

__global__ void scan3_kernel(int* __restrict__ outp, const int* __restrict__ bsum,
                             int n, int E) {
    int i = blockIdx.x * blockDim.x + threadIdx.x;
    if (i < n) outp[i] += bsum[i >> 10];
    if (i == 0) outp[n] = E;
}

// ------------------------------ small structs ------------------------------

struct alignas(4) U2 { u16 v[2]; };
struct alignas(8) U4 { u16 v[4]; };
struct alignas(16) U8 { u16 v[8]; };

// --------------- fused cast+quant of h (fp32 -> bf16 + biased u8) ----------
// One 64-lane group per row (128 feats): lane holds 2 floats.

__global__ __launch_bounds__(256) void castquant_f32_128(
    const float* __restrict__ h, u16* __restrict__ cat, int ldcat,
    const float* __restrict__ normv,
    u8* __restrict__ q, float* __restrict__ m, int N) {
    int row = blockIdx.x * 4 + (threadIdx.x >> 6);
    if (row >= N) return;
    int lane = threadIdx.x & 63;
    float2 f = *(const float2*)(h + (size_t)row * 128 + lane * 2);
    U2 o;
    o.v[0] = f2u(f.x);
    o.v[1] = f2u(f.y);
    *(U2*)(cat + (size_t)row * ldcat + lane * 2) = o;
    float mx = fmaxf(fabsf(f.x), fabsf(f.y));
    #pragma unroll
    for (int off = 32; off > 0; off >>= 1)
        mx = fmaxf(mx, __shfl_xor(mx, off, 64));
    float inv = mx > 0.f ? 127.f / mx : 0.f;
    u32 q0 = (u32)((int)rintf(f.x * inv) + 128);
    u32 q1 = (u32)((int)rintf(f.y * inv) + 128);
    *(unsigned short*)(q + (size_t)row * 128 + lane * 2) =
        (unsigned short)(q0 | (q1 << 8));
    if (lane == 0) m[row] = normv[row] * (mx * (1.f / 127.f));
}

// ------------------------- int8 row-quantized prop -------------------------
// BPL = bytes (features) per lane; D = 32*BPL. 64-lane group per dst node,
// split into two 32-lane halves, each half processes alternate edges.
// q stored biased (+128): acc = sum nm*qb - 128*sum nm  == sum nm*q.
// SGRP = scales per row (1 = row-wise, 8 = per-32-col groups from QMODE
// GEMM). Main loop: full 16-edge groups, colidx prefetched one group ahead.
// Tail: one masked clamped group. QOUT: fused re-quant of output row.

template <int BPL, int QOUT, int SGRP>
__global__ __launch_bounds__(256, 2) void prop_q8_kernel(
    const u8* __restrict__ qin, const float* __restrict__ m,
    u16* __restrict__ out, int ldout,
    const int* __restrict__ rowptr, const int* __restrict__ colidx,
    const float* __restrict__ normv, int N,
    u8* __restrict__ qout, float* __restrict__ mout) {
    constexpr int D = 32 * BPL;
    constexpr int NW = BPL / 4;            // u32 words per lane
    constexpr int UE = 8;                  // edges per half per group (16/group)
    int node = blockIdx.x * 4 + (threadIdx.x >> 6);
    if (node >= N) return;
    const int lane = threadIdx.x & 63;
    const int half = lane >> 5;
    const int l32 = lane & 31;
    const u32 laneoff = (u32)l32 * BPL;
    const u32 soff = (SGRP == 8) ? (u32)(l32 >> 2) : 0u;
    int s = rowptr[node], e = rowptr[node + 1];
    float acc[BPL];
    #pragma unroll
    for (int q = 0; q < BPL; ++q) acc[q] = 0.f;
    float msum = 0.f;
    const int nfull = (e - s) >> 4;        // full groups of 16 edges
    int p = s;
    if (nfull > 0) {
        int c[UE];
        #pragma unroll
        for (int u = 0; u < UE; ++u) c[u] = colidx[s + 2 * u + half];
        for (int g = 0; g < nfull; ++g) {
            u32 w[UE][NW];
            #pragma unroll
            for (int u = 0; u < UE; ++u) {
                u32 off = (u32)c[u] * D + laneoff;
                if (BPL == 8) {
                    uint2 gg = *(const uint2*)(qin + off);
                    w[u][0] = gg.x; w[u][1] = gg.y;
                } else {
                    w[u][0] = *(const u32*)(qin + off);
                }
            }
            float nm[UE];
            #pragma unroll
            for (int u = 0; u < UE; ++u) nm[u] = m[(u32)c[u] * SGRP + soff];
            // prefetch next group's colidx (wave-uniform branch)
            if (g + 1 < nfull) {
                int pn = s + (g + 1) * 16;
                #pragma unroll
                for (int u = 0; u < UE; ++u) c[u] = colidx[pn + 2 * u + half];
            }
            #pragma unroll
            for (int u = 0; u < UE; ++u) {
                msum += nm[u];
                #pragma unroll
                for (int t = 0; t < NW; ++t) {
                    u32 ww = w[u][t];
                    acc[4 * t + 0] += nm[u] * (float)(ww & 0xffu);
                    acc[4 * t + 1] += nm[u] * (float)((ww >> 8) & 0xffu);
                    acc[4 * t + 2] += nm[u] * (float)((ww >> 16) & 0xffu);
                    acc[4 * t + 3] += nm[u] * (float)(ww >> 24);
                }
            }
        }
        p = s + nfull * 16;
    }
    if (p < e) {
        // single masked clamped group for the tail (<16 edges)
        const int el = e - 1;
        int c[UE];
        #pragma unroll
        for (int u = 0; u < UE; ++u) {
            int idx = p + 2 * u + half;
            c[u] = colidx[idx < e ? idx : el];
        }
        u32 w[UE][NW];
        #pragma unroll
        for (int u = 0; u < UE; ++u) {
            u32 off = (u32)c[u] * D + laneoff;
            if (BPL == 8) {
                uint2 gg = *(const uint2*)(qin + off);
                w[u][0] = gg.x; w[u][1] = gg.y;
            } else {
                w[u][0] = *(const u32*)(qin + off);
            }
        }
        float nm[UE];
        #pragma unroll
        for (int u = 0; u < UE; ++u) {
            int idx = p + 2 * u + half;
            float mm = m[(u32)c[u] * SGRP + soff];
            nm[u] = idx < e ? mm : 0.f;
        }
        #pragma unroll
        for (int u = 0; u < UE; ++u) {
            msum += nm[u];
            #pragma unroll
            for (int t = 0; t < NW; ++t) {
                u32 ww = w[u][t];
                acc[4 * t + 0] += nm[u] * (float)(ww & 0xffu);
                acc[4 * t + 1] += nm[u] * (float)((ww >> 8) & 0xffu);
                acc[4 * t + 2] += nm[u] * (float)((ww >> 16) & 0xffu);
                acc[4 * t + 3] += nm[u] * (float)(ww >> 24);
            }
        }
    }
    // combine halves + bias correction + dst norm (lane^32 shares l32 ->
    // same scale group, so per-lane msum correction stays valid)
    #pragma unroll
    for (int q = 0; q < BPL; ++q) acc[q] += __shfl_xor(acc[q], 32, 64);
    msum += __shfl_xor(msum, 32, 64);
    float nn = normv[node];
    #pragma unroll
    for (int q = 0; q < BPL; ++q) acc[q] = nn * (acc[q] - 128.f * msum);
    if (half == 0) {
        if (BPL == 8) {
            U8 o;
            #pragma unroll
            for (int q = 0; q < 8; ++q) o.v[q] = f2u(acc[q]);
            *(U8*)(out + (size_t)node * ldout + l32 * 8) = o;
        } else {
            U4 o;
            #pragma unroll
            for (int q = 0; q < 4; ++q) o.v[q] = f2u(acc[q]);
            *(U4*)(out + (size_t)node * ldout + l32 * 4) = o;
        }
    }
    if (QOUT) {
        float mx = 0.f;
        #pragma unroll
        for (int q = 0; q < BPL; ++q) mx = fmaxf(mx, fabsf(acc[q]));
        #pragma unroll
        for (int off = 16; off > 0; off >>= 1)
            mx = fmaxf(mx, __shfl_xor(mx, off, 64));
        float inv = mx > 0.f ? 127.f / mx : 0.f;
        if (half == 0) {
            u32 b[BPL > 4 ? 8 : 4];
            #pragma unroll
            for (int q = 0; q < BPL; ++q)
                b[q] = (u32)((int)rintf(acc[q] * inv) + 128);
            if (BPL == 8) {
                uint2 g;
                g.x = b[0] | (b[1] << 8) | (b[2] << 16) | (b[3] << 24);
                g.y = b[4] | (b[5] << 8) | (b[6] << 16) | (b[7] << 24);
                *(uint2*)(qout + (size_t)node * D + l32 * 8) = g;
            } else {
                *(u32*)(qout + (size_t)node * D + l32 * 4) =
                    b[0] | (b[1] << 8) | (b[2] << 16) | (b[3] << 24);
            }
            if (lane == 0) mout[node] = nn * (mx * (1.f / 127.f));
        }
    }
}

// ------------------------------- MFMA GEMM ---------------------------------
// QMODE=0: Cout[M x 256] = [relu]( A @ Bt^T [+Cadd] [+bias] ) -> bf16
// QMODE=1: writes biased-u8 Qout[M x 256] + per-32-col scales
//          Mout[M x 8] = normv*absmax/127 (for SGRP=8 prop). Cout unused.
// Bt is [256 x KK] bf16 row-major. Tile 128x64, BK=32, 4 waves (2x2).
// 1-D grid, XCD-chunked swizzle, y-fastest decode (A-panel L2 reuse).
// XOR-swizzled LDS layouts: A chunk r*4+s holds k-seg s^((r>>1)&3); B chunk
// n*KC+j holds k-chunk j^(n&7). 16B chunks.

typedef __attribute__((ext_vector_type(8))) short bf16x8f;
typedef __attribute__((ext_vector_type(4))) float f32x4;

__device__ inline void async16(const void* g, void* l) {
    __builtin_amdgcn_global_load_lds(
        (__attribute__((address_space(1))) void*)(g),
        (__attribute__((address_space(3))) void*)(l), 16, 0, 0);
}

constexpr int GBM = 128, GBN = 64, GBK = 32;

__device__ inline void stageA_sw(const u16* __restrict__ A, int lda, int row0,
                                 int k0, u16* dst, int tid) {
    // LDS chunk c holds (row = c>>2, k-seg = (c&3) ^ ((row>>1)&3)).
    #pragma unroll
    for (int i = 0; i < 2; ++i) {
        int c = tid + i * 256;
        int row = c >> 2;
        int seg = (c & 3) ^ ((row >> 1) & 3);
        async16(A + (size_t)(row0 + row) * lda + k0 + seg * 8, dst + c * 8);
    }
}

template <int KK, int QMODE>
__global__ __launch_bounds__(256) void gemm_mfma(
    const u16* __restrict__ A, int lda,
    const u16* __restrict__ Bt,          // [256 x KK]
    const u16* __restrict__ Cadd,        // nullable, [Mpad x 256]
    const float* __restrict__ bias,      // nullable, [256]
    u16* __restrict__ Cout,              // QMODE=0: [Mpad x 256]
    u8* __restrict__ Qout,               // QMODE=1: [Mpad x 256]
    float* __restrict__ Mout,            // QMODE=1: [Mpad x 8]
    const float* __restrict__ normv,     // QMODE=1
    int M, int relu) {
    constexpr int KC = KK / 8;           // 16B chunks per B row
    __shared__ u16 Ab[2][GBM * GBK];
    __shared__ u16 Bs[GBN * KK];
    const int tid = threadIdx.x;
    const int lane = tid & 63;
    const int wave = tid >> 6;
    const int wm = wave >> 1, wn = wave & 1;
    // XCD-chunked swizzle (gridDim.x % 8 == 0), then y-fastest decode so the
    // 4 col-blocks sharing an A-panel are adjacent on one XCD.
    int nwg = gridDim.x;
    int q8c = nwg >> 3;
    int nb = (blockIdx.x & 7) * q8c + (blockIdx.x >> 3);
    const int row0 = (nb >> 2) * GBM;
    const int col0 = (nb & 3) * GBN;
    const int NOUT = 256;

    // stage B panel, swizzled: LDS chunk cb holds (n = cb/KC, j = (cb%KC)^(n&7))
    {
        const u16* srcB = Bt + (size_t)col0 * KK;
        #pragma unroll
        for (int i = 0; i < GBN * KC / 256; ++i) {
            int cb = tid + i * 256;
            int n = cb / KC;
            int j = (cb % KC) ^ (n & 7);
            async16(srcB + (size_t)n * KK + j * 8, &Bs[cb * 8]);
        }
    }
    stageA_sw(A, lda, row0, 0, Ab[0], tid);
    __syncthreads();

    f32x4 acc[4][2];
    #pragma unroll
    for (int mi = 0; mi < 4; ++mi)
        #pragma unroll
        for (int ni = 0; ni < 2; ++ni) acc[mi][ni] = (f32x4)0.f;

    constexpr int nk = KK / GBK;
    const int mb = lane & 15;
    const int seg = lane >> 4;           // k-seg within 32-wide tile (0..3)
    for (int ks = 0; ks < nk; ++ks) {
        int cur = ks & 1;
        if (ks + 1 < nk) stageA_sw(A, lda, row0, (ks + 1) * GBK, Ab[cur ^ 1], tid);
        bf16x8f a[4], b[2];
        #pragma unroll
        for (int mi = 0; mi < 4; ++mi) {
            int r = wm * 64 + mi * 16 + mb;
            int ca = r * 4 + (seg ^ ((r >> 1) & 3));
            a[mi] = *(const bf16x8f*)&Ab[cur][ca * 8];
        }
        #pragma unroll
        for (int ni = 0; ni < 2; ++ni) {
            int n = wn * 32 + ni * 16 + mb;
            int jk = ks * 4 + seg;
            int cb = n * KC + (jk ^ (n & 7));
            b[ni] = *(const bf16x8f*)&Bs[cb * 8];
        }
        #pragma unroll
        for (int mi = 0; mi < 4; ++mi)
            #pragma unroll
            for (int ni = 0; ni < 2; ++ni)
                acc[mi][ni] = __builtin_amdgcn_mfma_f32_16x16x32_bf16(
                    a[mi], b[ni], acc[mi][ni], 0, 0, 0);
        __syncthreads();
    }

    // epilogue: C/D layout col = lane&15, row = (lane>>4)*4 + r
    if (QMODE == 0) {
        #pragma unroll
        for (int mi = 0; mi < 4; ++mi) {
            #pragma unroll
            for (int r = 0; r < 4; ++r) {
                int row = row0 + wm * 64 + mi * 16 + (lane >> 4) * 4 + r;
                if (row < M) {
                    #pragma unroll
                    for (int ni = 0; ni < 2; ++ni) {
                        int col = col0 + wn * 32 + ni * 16 + (lane & 15);
                        float v = acc[mi][ni][r];
                        if (Cadd) v += u2f(Cadd[(size_t)row * NOUT + col]);
                        if (bias) v += bias[col];
                        if (relu) v = fmaxf(v, 0.f);
                        Cout[(size_t)row * NOUT + col] = f2u(v);
                    }
                }
            }
        }
    } else {
        // quantizing epilogue: per-(row, 32-col) scale; bytes staged in LDS
        u8* q8s = (u8*)Ab;   // 8 KB stage [128][64], Ab dead after k-loop
        float v[4][2][4];
        #pragma unroll
        for (int mi = 0; mi < 4; ++mi) {
            #pragma unroll
            for (int r = 0; r < 4; ++r) {
                int row = row0 + wm * 64 + mi * 16 + (lane >> 4) * 4 + r;
                bool ok = row < M;
                #pragma unroll
                for (int ni = 0; ni < 2; ++ni) {
                    int col = col0 + wn * 32 + ni * 16 + (lane & 15);
                    float x = acc[mi][ni][r];
                    if (Cadd && ok) x += u2f(Cadd[(size_t)row * NOUT + col]);
                    v[mi][ni][r] = x;
                }
            }
        }
        #pragma unroll
        for (int mi = 0; mi < 4; ++mi) {
            #pragma unroll
            for (int r = 0; r < 4; ++r) {
                float mx = fmaxf(fabsf(v[mi][0][r]), fabsf(v[mi][1][r]));
                #pragma unroll
                for (int off = 1; off < 16; off <<= 1)
                    mx = fmaxf(mx, __shfl_xor(mx, off, 64));
                float inv = mx > 0.f ? 127.f / mx : 0.f;
                int rl = wm * 64 + mi * 16 + (lane >> 4) * 4 + r;
                #pragma unroll
                for (int ni = 0; ni < 2; ++ni) {
                    int b = (int)rintf(v[mi][ni][r] * inv) + 128;
                    q8s[rl * 64 + wn * 32 + ni * 16 + (lane & 15)] = (u8)b;
                }
                if ((lane & 15) == 0) {
                    int row = row0 + rl;
                    if (row < M)
                        Mout[(size_t)row * 8 + (col0 >> 5) + wn] =
                            normv[row] * (mx * (1.f / 127.f));
                }
            }
        }
        __syncthreads();
        #pragma unroll
        for (int i = 0; i < 2; ++i) {
            int cidx = tid * 2 + i;          // 512 chunks of 16B
            int rl = cidx >> 2;
            int co = (cidx & 3) * 16;
            int row = row0 + rl;
            if (row < M)
                *(uint4*)(Qout + (size_t)row * 256 + col0 + co) =
                    *(const uint4*)(q8s + rl * 64 + co);
        }
    }
}

// Wt[n*K + k] = bf16(W[k*Nn + n])
__global__ void transpose_cast(const float* __restrict__ W, u16* __restrict__ Wt,
                               int K, int Nn) {
    int idx = blockIdx.x * blockDim.x + threadIdx.x;
    if (idx < K * Nn) {
        int n = idx / K, k = idx % K;
        Wt[idx] = f2u(W[(size_t)k * Nn + n]);
    }
}

// ------------------------------ pool + head --------------------------------

__global__ void pool_kernel(const u16* __restrict__ x, const int* __restrict__ gid,
                            float* __restrict__ pooled, int N, int HID) {
    int t = threadIdx.x;
    int n0 = blockIdx.x * 128;
    int n1 = n0 + 128 < N ? n0 + 128 : N;
    float cur = 0.f;
    int cg = gid[n0];
    for (int n = n0; n < n1; ++n) {
        int g = gid[n];
        if (g != cg) {
            atomicMax((int*)&pooled[(size_t)cg * HID + t], __float_as_int(cur));
            cg = g;
            cur = 0.f;
        }
        float v = u2f(x[(size_t)n * HID + t]);
        cur = cur > v ? cur : v;
    }
    atomicMax((int*)&pooled[(size_t)cg * HID + t], __float_as_int(cur));
}

__global__ void head_kernel(const float* __restrict__ pooled, const float* __restrict__ Wc,
                            const float* __restrict__ bc, float* __restrict__ out,
                            int HID, int C) {
    __shared__ float row[256];
    int g = blockIdx.x;
    int t = threadIdx.x;
    if (t < HID) row[t] = pooled[(size_t)g * HID + t];
    __syncthreads();
    if (t < C) {
        float s = bc[t];
        for (int k = 0; k < HID; ++k) s += row[k] * Wc[(size_t)k * C + t];
        out[(size_t)g * C + t] = s;
    }
}

// ------------------------------- launch ------------------------------------

extern "C" void kernel_launch(void* const* d_in, const int* in_sizes, int n_in,
                              void* d_out, int out_size, void* d_ws, size_t ws_size,
                              hipStream_t stream) {
    const float* h  = (const float*)d_in[0];
    const int* src  = (const int*)d_in[1];
    const int* dst  = (const int*)d_in[2];
    const int* gid  = (const int*)d_in[3];
    const float* W1 = (const float*)d_in[4];
    const float* b1 = (const float*)d_in[5];
    const float* W2 = (const float*)d_in[6];
    const float* b2 = (const float*)d_in[7];
    const float* Wc = (const float*)d_in[8];
    const float* bc = (const float*)d_in[9];
    float* out = (float*)d_out;

    const int N   = in_sizes[3];          // 100000
    const int E   = in_sizes[1];          // 3200000
    const int IN  = in_sizes[0] / N;      // 128
    const int HID = in_sizes[5];          // 256
    const int C   = in_sizes[9];          // 10
    const int G   = out_size / C;         // 64
    const int CAT = 3 * IN;               // 384
    const int Mpad = (N + 127) & ~127;    // 100096 (multiple of GBM)
    const int NB = (N + NPB - 1) / NPB;   // 782 buckets (<= NBMAX)
    const int CS = (E + NC - 1) / NC;     // 25000 edges/chunk

    char* wp = (char*)d_ws;
    auto alloc = [&](size_t bytes) {
        char* p = wp;
        wp += (bytes + 255) & ~(size_t)255;
        return p;
    };
    float* pooled = (float*)alloc((size_t)G * HID * sizeof(float));
    float* normv  = (float*)alloc((size_t)N * sizeof(float));
    float* mv     = (float*)alloc((size_t)N * sizeof(float));
    float* mv2    = (float*)alloc((size_t)N * sizeof(float));
    float* mv8    = (float*)alloc((size_t)Mpad * 8 * sizeof(float));
    int* rowptr   = (int*)alloc((size_t)(N + 1) * sizeof(int));
    int* bsum     = (int*)alloc(1024 * sizeof(int));
    int* Omat     = (int*)alloc((size_t)(NB * NC + 1) * sizeof(int));
    int* Hmat     = (int*)alloc((size_t)(NB * NC) * sizeof(int));
    int* colidx   = (int*)alloc((size_t)E * sizeof(int));
    u16* Wt1      = (u16*)alloc((size_t)CAT * HID * sizeof(u16));        // [256 x 384]
    u16* Wt2      = (u16*)alloc((size_t)3 * HID * HID * sizeof(u16));    // 3 x [256 x 256]
    u16* CAT1     = (u16*)alloc((size_t)Mpad * CAT * sizeof(u16));       // [h|Ph|P2h]
    u16* X1       = (u16*)alloc((size_t)Mpad * HID * sizeof(u16));
    u16* B2       = (u16*)alloc((size_t)Mpad * HID * sizeof(u16));
    u16* B1       = CAT1;                              // alias: CAT1 dead after GEMM1
    uint2* Earr   = (uint2*)CAT1;                      // alias: dead before cast writes
    u8* Q8L2      = (u8*)(CAT1 + (size_t)Mpad * HID);  // CAT1 tail, layer-2
    u8* Q8A       = (u8*)B2;                           // B2 dead during layer 1
    u8* Q8B       = (u8*)B2 + (size_t)Mpad * 128;      // second L1 q8 buffer

    // --- CSR build: counting sort (no global atomics) ---
    const int n2 = NB * NC;               // 100096
    countA_kernel<<<NC, 256, 0, stream>>>(dst, Hmat, E, CS, NB);
    scan1_kernel<<<(n2 + 1023) / 1024, 1024, 0, stream>>>(Hmat, Omat, bsum, n2);
    scan2_kernel<<<1, 1024, 0, stream>>>(bsum, (n2 + 1023) / 1024);
    scan3_kernel<<<(n2 + 255) / 256, 256, 0, stream>>>(Omat, bsum, n2, E);
    scatterC_kernel<<<NC, 256, 0, stream>>>(src, dst, Omat, Earr, E, CS, NB);
    fineD_kernel<<<NB, 256, 0, stream>>>(Earr, Omat, colidx, rowptr, normv, N, E, NB);

    // --- weight transpose + bf16 cast (small) ---
    transpose_cast<<<(CAT * HID + 255) / 256, 256, 0, stream>>>(W1, Wt1, CAT, HID);
    for (int s2 = 0; s2 < 3; ++s2)
        transpose_cast<<<(HID * HID + 255) / 256, 256, 0, stream>>>(
            W2 + (size_t)s2 * HID * HID, Wt2 + (size_t)s2 * HID * HID, HID, HID);

    // --- layer 1: CAT1 = [bf16(h) | P h | P^2 h]; X1 = relu(CAT1@W1+b1) ---
    int pb = (N + 3) / 4;
    castquant_f32_128<<<pb, 256, 0, stream>>>(h, CAT1, CAT, normv, Q8A, mv, N);
    prop_q8_kernel<4, 1, 1><<<pb, 256, 0, stream>>>(Q8A, mv, CAT1 + IN, CAT,
                                                    rowptr, colidx, normv, N, Q8B, mv2);
    prop_q8_kernel<4, 0, 1><<<pb, 256, 0, stream>>>(Q8B, mv2, CAT1 + 2 * IN, CAT,
                                                    rowptr, colidx, normv, N,
                                                    nullptr, nullptr);
    int nwg = (Mpad / GBM) * (HID / GBN);   // 3128, multiple of 8
    gemm_mfma<384, 0><<<nwg, 256, 0, stream>>>(CAT1, CAT, Wt1, nullptr, b1, X1,
                                               nullptr, nullptr, nullptr, N, 1);

    // --- layer 2 (commuted): X2 = relu(X1@W2a + P(X1@W2b + P(X1@W2c)) + b2) ---
    gemm_mfma<256, 1><<<nwg, 256, 0, stream>>>(X1, HID, Wt2 + (size_t)2 * HID * HID,
                                               nullptr, nullptr, nullptr,
                                               Q8L2, mv8, normv, N, 0);
    prop_q8_kernel<8, 0, 8><<<pb, 256, 0, stream>>>(Q8L2, mv8, B2, HID,
                                                    rowptr, colidx, normv, N,
                                                    nullptr, nullptr);
    gemm_mfma<256, 1><<<nwg, 256, 0, stream>>>(X1, HID, Wt2 + (size_t)HID * HID,
                                               B2, nullptr, nullptr,
                                               Q8L2, mv8, normv, N, 0);
    prop_q8_kernel<8, 0, 8><<<pb, 256, 0, stream>>>(Q8L2, mv8, B2, HID,
                                                    rowptr, colidx, normv, N,
                                                    nullptr, nullptr);
    gemm_mfma<256, 0><<<nwg, 256, 0, stream>>>(X1, HID, Wt2, B2, b2, B1,
                                               nullptr, nullptr, nullptr, N, 1);

    // --- pool + head ---
    hipMemsetAsync(pooled, 0, (size_t)G * HID * sizeof(float), stream);
    pool_kernel<<<(N + 127) / 128, HID, 0, stream>>>(B1, gid, pooled, N, HID);
    head_kernel<<<G, HID, 0, stream>>>(pooled, Wc, bc, out, HID, C);
}

// Round 5
// 1049.510 us; speedup vs baseline: 1.0261x; 1.0261x over previous
//
#include <hip/hip_runtime.h>
#include <hip/hip_bf16.h>

// ---------------------------------------------------------------------------
// TAGConv (K=2) x2 + segment-max pool + linear head. bf16 intermediates,
// fp32 accumulate, int8 row-quantized gathers for ALL props. Layer-2
// commuted: z2@W2 = X1@W2a + P(X1@W2b + P(X1@W2c)). CSR via counting sort.
// Round 14: R4's SGRP=8 scale gather added +134MB HBM (3.2MB scale table
// thrashes L2 vs 400KB row table) -> reverted to R3 numerics (prop 116us).
// GEMM accounting says ~500us across 5 GEMMs and the 128x64 tile is
// LDS-read-bound 2.2x (24KB LDS->VGPR per 128cy of MFMA). New GEMM:
// 128x128 tile, 4 waves x (64x64 = 4x4 acc), A AND B double-buffered
// 32-K panels via XOR-swizzled global_load_lds (32KB LDS), bijective
// XCD-chunk swizzle + col-fastest decode for A-panel L2 reuse.
// ---------------------------------------------------------------------------

typedef unsigned short u16;
typedef unsigned int u32;
typedef unsigned char u8;

__device__ inline float u2f(u16 u) { return __uint_as_float(((u32)u) << 16); }
__device__ inline u16 f2u(float f) {
    __hip_bfloat16 b = __float2bfloat16(f);
    return *reinterpret_cast<u16*>(&b);
}

// ---------------------- CSR build: counting sort ---------------------------
// NPB = 128 nodes per bucket, NC = 128 edge chunks. NB = ceil(N/NPB) <= 784.

constexpr int NPB = 128, NC = 128, NBMAX = 784;

__global__ __launch_bounds__(256) void countA_kernel(
    const int* __restrict__ dst, int* __restrict__ Hmat, int E, int CS, int NB) {
    __shared__ int hist[NBMAX];
    int tid = threadIdx.x;
    for (int b = tid; b < NB; b += 256) hist[b] = 0;
    __syncthreads();
    int base = blockIdx.x * CS;
    int end = base + CS < E ? base + CS : E;
    for (int i = base + tid; i < end; i += 256) {
        int d = __builtin_nontemporal_load(dst + i);
        atomicAdd(&hist[d >> 7], 1);
    }
    __syncthreads();
    for (int b = tid; b < NB; b += 256) Hmat[b * NC + blockIdx.x] = hist[b];
}

__global__ __launch_bounds__(256) void scatterC_kernel(
    const int* __restrict__ src, const int* __restrict__ dst,
    const int* __restrict__ Omat, uint2* __restrict__ Earr,
    int E, int CS, int NB) {
    __shared__ int cur[NBMAX];
    int tid = threadIdx.x;
    int c = blockIdx.x;
    for (int b = tid; b < NB; b += 256) cur[b] = Omat[b * NC + c];
    __syncthreads();
    int base = c * CS;
    int end = base + CS < E ? base + CS : E;
    for (int i = base + tid; i < end; i += 256) {
        int d = __builtin_nontemporal_load(dst + i);
        int s = __builtin_nontemporal_load(src + i);
        int pos = atomicAdd(&cur[d >> 7], 1);
        uint2 e;
        e.x = (u32)s;
        e.y = (u32)(d & (NPB - 1));
        Earr[pos] = e;
    }
}

// One block per bucket: local deg count -> rowptr/normv, then colidx scatter.
__global__ __launch_bounds__(256) void fineD_kernel(
    const uint2* __restrict__ Earr, const int* __restrict__ Omat,
    int* __restrict__ colidx, int* __restrict__ rowptr,
    float* __restrict__ normv, int N, int E, int NB) {
    __shared__ int cnt[NPB];
    __shared__ int scn[NPB];
    __shared__ int cur2[NPB];
    int tid = threadIdx.x;
    int b = blockIdx.x;
    int base = Omat[b * NC];
    int end = Omat[(b + 1) * NC];   // Omat[NB*NC] = E (scan tail)
    if (tid < NPB) cnt[tid] = 0;
    __syncthreads();
    for (int i = base + tid; i < end; i += 256)
        atomicAdd(&cnt[Earr[i].y], 1);
    __syncthreads();
    if (tid < NPB) scn[tid] = cnt[tid];
    __syncthreads();
    for (int off = 1; off < NPB; off <<= 1) {
        int v = (tid < NPB && tid >= off) ? scn[tid - off] : 0;
        __syncthreads();
        if (tid < NPB) scn[tid] += v;
        __syncthreads();
    }
    int node0 = b * NPB;
    if (tid < NPB) {
        int excl = scn[tid] - cnt[tid];
        cur2[tid] = base + excl;
        int node = node0 + tid;
        if (node < N) {
            rowptr[node] = base + excl;
            int d = cnt[tid];
            float fd = d < 1 ? 1.0f : (float)d;
            normv[node] = rsqrtf(fd);
        }
    }
    if (b == 0 && tid == 0) rowptr[N] = E;
    __syncthreads();
    for (int i = base + tid; i < end; i += 256) {
        uint2 e = Earr[i];
        int pos = atomicAdd(&cur2[e.y], 1);
        colidx[pos] = (int)e.x;
    }
}

// Multi-block scan.
__global__ void scan1_kernel(const int* __restrict__ in, int* __restrict__ outp,
                             int* __restrict__ bsum, int n) {
    __shared__ int sd[1024];
    int t = threadIdx.x;
    int i = blockIdx.x * 1024 + t;
    int v = (i < n) ? in[i] : 0;
    sd[t] = v;
    __syncthreads();
    for (int off = 1; off < 1024; off <<= 1) {
        int x = (t >= off) ? sd[t - off] : 0;
        __syncthreads();
        sd[t] += x;
        __syncthreads();
    }
    if (i < n) outp[i] = sd[t] - v;
    if (t == 1023) bsum[blockIdx.x] = sd[t];
}

__global__ void scan2_kernel(int* __restrict__ bsum, int nb) {
    __shared__ int sd[1024];
    int t = threadIdx.x;
    int v = (t < nb) ? bsum[t] : 0;
    sd[t] = v;
    __syncthreads();
    for (int off = 1; off < 1024; off <<= 1) {
        int x = (t >= off) ? sd[t - off] : 0;
        __syncthreads();
        sd[t] += x;
        __syncthreads();
    }
    if (t < nb) bsum[t] = sd[t] - v;
}

__global__ void scan3_kernel(int* __restrict__ outp, const int* __restrict__ bsum,
                             int n, int E) {
    int i = blockIdx.x * blockDim.x + threadIdx.x;
    if (i < n) outp[i] += bsum[i >> 10];
    if (i == 0) outp[n] = E;
}

// ------------------------------ small structs ------------------------------

struct alignas(4) U2 { u16 v[2]; };
struct alignas(8) U4 { u16 v[4]; };
struct alignas(16) U8 { u16 v[8]; };

// --------------- fused cast+quant of h (fp32 -> bf16 + biased u8) ----------
// One 64-lane group per row (128 feats): lane holds 2 floats.

__global__ __launch_bounds__(256) void castquant_f32_128(
    const float* __restrict__ h, u16* __restrict__ cat, int ldcat,
    const float* __restrict__ normv,
    u8* __restrict__ q, float* __restrict__ m, int N) {
    int row = blockIdx.x * 4 + (threadIdx.x >> 6);
    if (row >= N) return;
    int lane = threadIdx.x & 63;
    float2 f = *(const float2*)(h + (size_t)row * 128 + lane * 2);
    U2 o;
    o.v[0] = f2u(f.x);
    o.v[1] = f2u(f.y);
    *(U2*)(cat + (size_t)row * ldcat + lane * 2) = o;
    float mx = fmaxf(fabsf(f.x), fabsf(f.y));
    #pragma unroll
    for (int off = 32; off > 0; off >>= 1)
        mx = fmaxf(mx, __shfl_xor(mx, off, 64));
    float inv = mx > 0.f ? 127.f / mx : 0.f;
    u32 q0 = (u32)((int)rintf(f.x * inv) + 128);
    u32 q1 = (u32)((int)rintf(f.y * inv) + 128);
    *(unsigned short*)(q + (size_t)row * 128 + lane * 2) =
        (unsigned short)(q0 | (q1 << 8));
    if (lane == 0) m[row] = normv[row] * (mx * (1.f / 127.f));
}

// ----------------- quant bf16[256] -> biased u8 (after GEMM) ---------------

__global__ __launch_bounds__(256) void quant_bf16_256(
    const u16* __restrict__ x, const float* __restrict__ normv,
    u8* __restrict__ q, float* __restrict__ m, int N) {
    int row = blockIdx.x * 4 + (threadIdx.x >> 6);
    if (row >= N) return;
    int lane = threadIdx.x & 63;
    U4 v = *(const U4*)(x + (size_t)row * 256 + lane * 4);
    float f[4];
    #pragma unroll
    for (int i = 0; i < 4; ++i) f[i] = u2f(v.v[i]);
    float mx = fmaxf(fmaxf(fabsf(f[0]), fabsf(f[1])),
                     fmaxf(fabsf(f[2]), fabsf(f[3])));
    #pragma unroll
    for (int off = 32; off > 0; off >>= 1)
        mx = fmaxf(mx, __shfl_xor(mx, off, 64));
    float inv = mx > 0.f ? 127.f / mx : 0.f;
    u32 b0 = (u32)((int)rintf(f[0] * inv) + 128);
    u32 b1 = (u32)((int)rintf(f[1] * inv) + 128);
    u32 b2 = (u32)((int)rintf(f[2] * inv) + 128);
    u32 b3 = (u32)((int)rintf(f[3] * inv) + 128);
    *(u32*)(q + (size_t)row * 256 + lane * 4) =
        b0 | (b1 << 8) | (b2 << 16) | (b3 << 24);
    if (lane == 0) m[row] = normv[row] * (mx * (1.f / 127.f));
}

// ------------------------- int8 row-quantized prop -------------------------
// BPL = bytes (features) per lane; D = 32*BPL. 64-lane group per dst node,
// split into two 32-lane halves, each half processes alternate edges.
// q stored biased (+128): acc = sum nm*qb - 128*sum nm  == sum nm*q.
// Main loop: full 16-edge groups, no per-edge masking (bounds are
// wave-uniform), colidx prefetched one group ahead. Tail: one masked
// clamped group. QOUT: fused re-quant of output row.

template <int BPL, int QOUT>
__global__ __launch_bounds__(256, 2) void prop_q8_kernel(
    const u8* __restrict__ qin, const float* __restrict__ m,
    u16* __restrict__ out, int ldout,
    const int* __restrict__ rowptr, const int* __restrict__ colidx,
    const float* __restrict__ normv, int N,
    u8* __restrict__ qout, float* __restrict__ mout) {
    constexpr int D = 32 * BPL;
    constexpr int NW = BPL / 4;            // u32 words per lane
    constexpr int UE = 8;                  // edges per half per group (16/group)
    int node = blockIdx.x * 4 + (threadIdx.x >> 6);
    if (node >= N) return;
    const int lane = threadIdx.x & 63;
    const int half = lane >> 5;
    const int l32 = lane & 31;
    const u32 laneoff = (u32)l32 * BPL;
    int s = rowptr[node], e = rowptr[node + 1];
    float acc[BPL];
    #pragma unroll
    for (int q = 0; q < BPL; ++q) acc[q] = 0.f;
    float msum = 0.f;
    const int nfull = (e - s) >> 4;        // full groups of 16 edges
    int p = s;
    if (nfull > 0) {
        int c[UE];
        #pragma unroll
        for (int u = 0; u < UE; ++u) c[u] = colidx[s + 2 * u + half];
        for (int g = 0; g < nfull; ++g) {
            u32 w[UE][NW];
            #pragma unroll
            for (int u = 0; u < UE; ++u) {
                u32 off = (u32)c[u] * D + laneoff;
                if (BPL == 8) {
                    uint2 gg = *(const uint2*)(qin + off);
                    w[u][0] = gg.x; w[u][1] = gg.y;
                } else {
                    w[u][0] = *(const u32*)(qin + off);
                }
            }
            float nm[UE];
            #pragma unroll
            for (int u = 0; u < UE; ++u) nm[u] = m[c[u]];
            // prefetch next group's colidx (wave-uniform branch)
            if (g + 1 < nfull) {
                int pn = s + (g + 1) * 16;
                #pragma unroll
                for (int u = 0; u < UE; ++u) c[u] = colidx[pn + 2 * u + half];
            }
            #pragma unroll
            for (int u = 0; u < UE; ++u) {
                msum += nm[u];
                #pragma unroll
                for (int t = 0; t < NW; ++t) {
                    u32 ww = w[u][t];
                    acc[4 * t + 0] += nm[u] * (float)(ww & 0xffu);
                    acc[4 * t + 1] += nm[u] * (float)((ww >> 8) & 0xffu);
                    acc[4 * t + 2] += nm[u] * (float)((ww >> 16) & 0xffu);
                    acc[4 * t + 3] += nm[u] * (float)(ww >> 24);
                }
            }
        }
        p = s + nfull * 16;
    }
    if (p < e) {
        // single masked clamped group for the tail (<16 edges)
        const int el = e - 1;
        int c[UE];
        #pragma unroll
        for (int u = 0; u < UE; ++u) {
            int idx = p + 2 * u + half;
            c[u] = colidx[idx < e ? idx : el];
        }
        u32 w[UE][NW];
        #pragma unroll
        for (int u = 0; u < UE; ++u) {
            u32 off = (u32)c[u] * D + laneoff;
            if (BPL == 8) {
                uint2 gg = *(const uint2*)(qin + off);
                w[u][0] = gg.x; w[u][1] = gg.y;
            } else {
                w[u][0] = *(const u32*)(qin + off);
            }
        }
        float nm[UE];
        #pragma unroll
        for (int u = 0; u < UE; ++u) {
            int idx = p + 2 * u + half;
            float mm = m[c[u]];
            nm[u] = idx < e ? mm : 0.f;
        }
        #pragma unroll
        for (int u = 0; u < UE; ++u) {
            msum += nm[u];
            #pragma unroll
            for (int t = 0; t < NW; ++t) {
                u32 ww = w[u][t];
                acc[4 * t + 0] += nm[u] * (float)(ww & 0xffu);
                acc[4 * t + 1] += nm[u] * (float)((ww >> 8) & 0xffu);
                acc[4 * t + 2] += nm[u] * (float)((ww >> 16) & 0xffu);
                acc[4 * t + 3] += nm[u] * (float)(ww >> 24);
            }
        }
    }
    // combine halves + bias correction + dst norm
    #pragma unroll
    for (int q = 0; q < BPL; ++q) acc[q] += __shfl_xor(acc[q], 32, 64);
    msum += __shfl_xor(msum, 32, 64);
    float nn = normv[node];
    #pragma unroll
    for (int q = 0; q < BPL; ++q) acc[q] = nn * (acc[q] - 128.f * msum);
    if (half == 0) {
        if (BPL == 8) {
            U8 o;
            #pragma unroll
            for (int q = 0; q < 8; ++q) o.v[q] = f2u(acc[q]);
            *(U8*)(out + (size_t)node * ldout + l32 * 8) = o;
        } else {
            U4 o;
            #pragma unroll
            for (int q = 0; q < 4; ++q) o.v[q] = f2u(acc[q]);
            *(U4*)(out + (size_t)node * ldout + l32 * 4) = o;
        }
    }
    if (QOUT) {
        float mx = 0.f;
        #pragma unroll
        for (int q = 0; q < BPL; ++q) mx = fmaxf(mx, fabsf(acc[q]));
        #pragma unroll
        for (int off = 16; off > 0; off >>= 1)
            mx = fmaxf(mx, __shfl_xor(mx, off, 64));
        float inv = mx > 0.f ? 127.f / mx : 0.f;
        if (half == 0) {
            u32 b[BPL > 4 ? 8 : 4];
            #pragma unroll
            for (int q = 0; q < BPL; ++q)
                b[q] = (u32)((int)rintf(acc[q] * inv) + 128);
            if (BPL == 8) {
                uint2 g;
                g.x = b[0] | (b[1] << 8) | (b[2] << 16) | (b[3] << 24);
                g.y = b[4] | (b[5] << 8) | (b[6] << 16) | (b[7] << 24);
                *(uint2*)(qout + (size_t)node * D + l32 * 8) = g;
            } else {
                *(u32*)(qout + (size_t)node * D + l32 * 4) =
                    b[0] | (b[1] << 8) | (b[2] << 16) | (b[3] << 24);
            }
            if (lane == 0) mout[node] = nn * (mx * (1.f / 127.f));
        }
    }
}

// ------------------------------- MFMA GEMM ---------------------------------
// Cout[M x 256] = [relu]( A(bf16,[Mpad x lda]) @ Bt^T [+Cadd] [+bias] ) -> bf16
// Bt is [256 x KK] bf16 row-major. Tile 128x128, BK=32, 4 waves (2x2),
// 64x64 per wave (4x4 acc). A and B both double-buffered 32-K panels via
// XOR-swizzled global_load_lds (chunk c holds row=c>>2, seg=(c&3)^((row>>1)&3)).
// 1-D grid with bijective XCD-chunk swizzle, col-fastest decode.

typedef __attribute__((ext_vector_type(8))) short bf16x8f;
typedef __attribute__((ext_vector_type(4))) float f32x4;

__device__ inline void async16(const void* g, void* l) {
    __builtin_amdgcn_global_load_lds(
        (__attribute__((address_space(1))) void*)(g),
        (__attribute__((address_space(3))) void*)(l), 16, 0, 0);
}

constexpr int GBM = 128, GBN = 128, GBK = 32;

// stage a [128 x 32] bf16 panel (row-major, leading dim ldp) into LDS
__device__ inline void stage_panel(const u16* __restrict__ P, int ldp, int row0,
                                   int k0, u16* dst, int tid) {
    #pragma unroll
    for (int i = 0; i < 2; ++i) {
        int c = tid + i * 256;
        int row = c >> 2;
        int seg = (c & 3) ^ ((row >> 1) & 3);
        async16(P + (size_t)(row0 + row) * ldp + k0 + seg * 8, dst + c * 8);
    }
}

template <int KK>
__global__ __launch_bounds__(256) void gemm_mfma(
    const u16* __restrict__ A, int lda,
    const u16* __restrict__ Bt,          // [256 x KK]
    const u16* __restrict__ Cadd,        // nullable, [Mpad x 256]
    const float* __restrict__ bias,      // nullable, [256]
    u16* __restrict__ Cout,              // [Mpad x 256]
    int M, int relu) {
    __shared__ u16 Ab[2][GBM * GBK];
    __shared__ u16 Bb[2][GBN * GBK];
    const int tid = threadIdx.x;
    const int lane = tid & 63;
    const int wave = tid >> 6;
    const int wm = wave >> 1, wn = wave & 1;
    // bijective XCD-chunk swizzle (any grid size), then col-fastest decode
    // so the 2 col-blocks sharing an A-panel run adjacently on one XCD.
    int nwg = gridDim.x;
    int qq = nwg >> 3, rr = nwg & 7;
    int xcd = blockIdx.x & 7, wi = blockIdx.x >> 3;
    int nb = (xcd < rr ? xcd * (qq + 1) : rr * (qq + 1) + (xcd - rr) * qq) + wi;
    const int row0 = (nb >> 1) * GBM;
    const int col0 = (nb & 1) * GBN;
    const int NOUT = 256;

    stage_panel(A, lda, row0, 0, Ab[0], tid);
    stage_panel(Bt, KK, col0, 0, Bb[0], tid);
    __syncthreads();

    f32x4 acc[4][4];
    #pragma unroll
    for (int mi = 0; mi < 4; ++mi)
        #pragma unroll
        for (int ni = 0; ni < 4; ++ni) acc[mi][ni] = (f32x4)0.f;

    constexpr int nk = KK / GBK;
    const int mb = lane & 15;
    const int seg = lane >> 4;           // k-seg within 32-wide tile (0..3)
    for (int ks = 0; ks < nk; ++ks) {
        int cur = ks & 1;
        if (ks + 1 < nk) {
            stage_panel(A, lda, row0, (ks + 1) * GBK, Ab[cur ^ 1], tid);
            stage_panel(Bt, KK, col0, (ks + 1) * GBK, Bb[cur ^ 1], tid);
        }
        bf16x8f a[4], b[4];
        #pragma unroll
        for (int mi = 0; mi < 4; ++mi) {
            int r = wm * 64 + mi * 16 + mb;
            int ca = r * 4 + (seg ^ ((r >> 1) & 3));
            a[mi] = *(const bf16x8f*)&Ab[cur][ca * 8];
        }
        #pragma unroll
        for (int ni = 0; ni < 4; ++ni) {
            int n = wn * 64 + ni * 16 + mb;
            int cb = n * 4 + (seg ^ ((n >> 1) & 3));
            b[ni] = *(const bf16x8f*)&Bb[cur][cb * 8];
        }
        #pragma unroll
        for (int mi = 0; mi < 4; ++mi)
            #pragma unroll
            for (int ni = 0; ni < 4; ++ni)
                acc[mi][ni] = __builtin_amdgcn_mfma_f32_16x16x32_bf16(
                    a[mi], b[ni], acc[mi][ni], 0, 0, 0);
        __syncthreads();
    }

    // epilogue: C/D layout col = lane&15, row = (lane>>4)*4 + r
    #pragma unroll
    for (int mi = 0; mi < 4; ++mi) {
        #pragma unroll
        for (int r = 0; r < 4; ++r) {
            int row = row0 + wm * 64 + mi * 16 + (lane >> 4) * 4 + r;
            if (row < M) {
                #pragma unroll
                for (int ni = 0; ni < 4; ++ni) {
                    int col = col0 + wn * 64 + ni * 16 + (lane & 15);
                    float v = acc[mi][ni][r];
                    if (Cadd) v += u2f(Cadd[(size_t)row * NOUT + col]);
                    if (bias) v += bias[col];
                    if (relu) v = fmaxf(v, 0.f);
                    Cout[(size_t)row * NOUT + col] = f2u(v);
                }
            }
        }
    }
}

// Wt[n*K + k] = bf16(W[k*Nn + n])
__global__ void transpose_cast(const float* __restrict__ W, u16* __restrict__ Wt,
                               int K, int Nn) {
    int idx = blockIdx.x * blockDim.x + threadIdx.x;
    if (idx < K * Nn) {
        int n = idx / K, k = idx % K;
        Wt[idx] = f2u(W[(size_t)k * Nn + n]);
    }
}

// ------------------------------ pool + head --------------------------------

__global__ void pool_kernel(const u16* __restrict__ x, const int* __restrict__ gid,
                            float* __restrict__ pooled, int N, int HID) {
    int t = threadIdx.x;
    int n0 = blockIdx.x * 128;
    int n1 = n0 + 128 < N ? n0 + 128 : N;
    float cur = 0.f;
    int cg = gid[n0];
    for (int n = n0; n < n1; ++n) {
        int g = gid[n];
        if (g != cg) {
            atomicMax((int*)&pooled[(size_t)cg * HID + t], __float_as_int(cur));
            cg = g;
            cur = 0.f;
        }
        float v = u2f(x[(size_t)n * HID + t]);
        cur = cur > v ? cur : v;
    }
    atomicMax((int*)&pooled[(size_t)cg * HID + t], __float_as_int(cur));
}

__global__ void head_kernel(const float* __restrict__ pooled, const float* __restrict__ Wc,
                            const float* __restrict__ bc, float* __restrict__ out,
                            int HID, int C) {
    __shared__ float row[256];
    int g = blockIdx.x;
    int t = threadIdx.x;
    if (t < HID) row[t] = pooled[(size_t)g * HID + t];
    __syncthreads();
    if (t < C) {
        float s = bc[t];
        for (int k = 0; k < HID; ++k) s += row[k] * Wc[(size_t)k * C + t];
        out[(size_t)g * C + t] = s;
    }
}

// ------------------------------- launch ------------------------------------

extern "C" void kernel_launch(void* const* d_in, const int* in_sizes, int n_in,
                              void* d_out, int out_size, void* d_ws, size_t ws_size,
                              hipStream_t stream) {
    const float* h  = (const float*)d_in[0];
    const int* src  = (const int*)d_in[1];
    const int* dst  = (const int*)d_in[2];
    const int* gid  = (const int*)d_in[3];
    const float* W1 = (const float*)d_in[4];
    const float* b1 = (const float*)d_in[5];
    const float* W2 = (const float*)d_in[6];
    const float* b2 = (const float*)d_in[7];
    const float* Wc = (const float*)d_in[8];
    const float* bc = (const float*)d_in[9];
    float* out = (float*)d_out;

    const int N   = in_sizes[3];          // 100000
    const int E   = in_sizes[1];          // 3200000
    const int IN  = in_sizes[0] / N;      // 128
    const int HID = in_sizes[5];          // 256
    const int C   = in_sizes[9];          // 10
    const int G   = out_size / C;         // 64
    const int CAT = 3 * IN;               // 384
    const int Mpad = (N + 127) & ~127;    // 100096 (multiple of GBM)
    const int NB = (N + NPB - 1) / NPB;   // 782 buckets (<= NBMAX)
    const int CS = (E + NC - 1) / NC;     // 25000 edges/chunk

    char* wp = (char*)d_ws;
    auto alloc = [&](size_t bytes) {
        char* p = wp;
        wp += (bytes + 255) & ~(size_t)255;
        return p;
    };
    float* pooled = (float*)alloc((size_t)G * HID * sizeof(float));
    float* normv  = (float*)alloc((size_t)N * sizeof(float));
    float* mv     = (float*)alloc((size_t)N * sizeof(float));
    float* mv2    = (float*)alloc((size_t)N * sizeof(float));
    int* rowptr   = (int*)alloc((size_t)(N + 1) * sizeof(int));
    int* bsum     = (int*)alloc(1024 * sizeof(int));
    int* Omat     = (int*)alloc((size_t)(NB * NC + 1) * sizeof(int));
    int* Hmat     = (int*)alloc((size_t)(NB * NC) * sizeof(int));
    int* colidx   = (int*)alloc((size_t)E * sizeof(int));
    u16* Wt1      = (u16*)alloc((size_t)CAT * HID * sizeof(u16));        // [256 x 384]
    u16* Wt2      = (u16*)alloc((size_t)3 * HID * HID * sizeof(u16));    // 3 x [256 x 256]
    u16* CAT1     = (u16*)alloc((size_t)Mpad * CAT * sizeof(u16));       // [h|Ph|P2h]
    u16* X1       = (u16*)alloc((size_t)Mpad * HID * sizeof(u16));
    u16* B2       = (u16*)alloc((size_t)Mpad * HID * sizeof(u16));
    u16* B1       = CAT1;                              // alias: CAT1 dead after GEMM1
    uint2* Earr   = (uint2*)CAT1;                      // alias: dead before cast writes
    u8* Q8L2      = (u8*)(CAT1 + (size_t)Mpad * HID);  // CAT1 tail, layer-2
    u8* Q8A       = (u8*)B2;                           // B2 dead during layer 1
    u8* Q8B       = (u8*)B2 + (size_t)Mpad * 128;      // second L1 q8 buffer

    // --- CSR build: counting sort (no global atomics) ---
    const int n2 = NB * NC;               // 100096
    countA_kernel<<<NC, 256, 0, stream>>>(dst, Hmat, E, CS, NB);
    scan1_kernel<<<(n2 + 1023) / 1024, 1024, 0, stream>>>(Hmat, Omat, bsum, n2);
    scan2_kernel<<<1, 1024, 0, stream>>>(bsum, (n2 + 1023) / 1024);
    scan3_kernel<<<(n2 + 255) / 256, 256, 0, stream>>>(Omat, bsum, n2, E);
    scatterC_kernel<<<NC, 256, 0, stream>>>(src, dst, Omat, Earr, E, CS, NB);
    fineD_kernel<<<NB, 256, 0, stream>>>(Earr, Omat, colidx, rowptr, normv, N, E, NB);

    // --- weight transpose + bf16 cast (small) ---
    transpose_cast<<<(CAT * HID + 255) / 256, 256, 0, stream>>>(W1, Wt1, CAT, HID);
    for (int s2 = 0; s2 < 3; ++s2)
        transpose_cast<<<(HID * HID + 255) / 256, 256, 0, stream>>>(
            W2 + (size_t)s2 * HID * HID, Wt2 + (size_t)s2 * HID * HID, HID, HID);

    // --- layer 1: CAT1 = [bf16(h) | P h | P^2 h]; X1 = relu(CAT1@W1+b1) ---
    int pb = (N + 3) / 4;
    castquant_f32_128<<<pb, 256, 0, stream>>>(h, CAT1, CAT, normv, Q8A, mv, N);
    prop_q8_kernel<4, 1><<<pb, 256, 0, stream>>>(Q8A, mv, CAT1 + IN, CAT,
                                                 rowptr, colidx, normv, N, Q8B, mv2);
    prop_q8_kernel<4, 0><<<pb, 256, 0, stream>>>(Q8B, mv2, CAT1 + 2 * IN, CAT,
                                                 rowptr, colidx, normv, N,
                                                 nullptr, nullptr);
    int nwg = (Mpad / GBM) * (HID / GBN);   // 782 * 2 = 1564
    gemm_mfma<384><<<nwg, 256, 0, stream>>>(CAT1, CAT, Wt1, nullptr, b1, X1, N, 1);

    // --- layer 2 (commuted): X2 = relu(X1@W2a + P(X1@W2b + P(X1@W2c)) + b2) ---
    gemm_mfma<256><<<nwg, 256, 0, stream>>>(X1, HID, Wt2 + (size_t)2 * HID * HID,
                                            nullptr, nullptr, B1, N, 0);
    quant_bf16_256<<<pb, 256, 0, stream>>>(B1, normv, Q8L2, mv, N);
    prop_q8_kernel<8, 0><<<pb, 256, 0, stream>>>(Q8L2, mv, B2, HID,
                                                 rowptr, colidx, normv, N,
                                                 nullptr, nullptr);
    gemm_mfma<256><<<nwg, 256, 0, stream>>>(X1, HID, Wt2 + (size_t)HID * HID,
                                            B2, nullptr, B1, N, 0);
    quant_bf16_256<<<pb, 256, 0, stream>>>(B1, normv, Q8L2, mv, N);
    prop_q8_kernel<8, 0><<<pb, 256, 0, stream>>>(Q8L2, mv, B2, HID,
                                                 rowptr, colidx, normv, N,
                                                 nullptr, nullptr);
    gemm_mfma<256><<<nwg, 256, 0, stream>>>(X1, HID, Wt2, B2, b2, B1, N, 1);

    // --- pool + head ---
    hipMemsetAsync(pooled, 0, (size_t)G * HID * sizeof(float), stream);
    pool_kernel<<<(N + 127) / 128, HID, 0, stream>>>(B1, gid, pooled, N, HID);
    head_kernel<<<G, HID, 0, stream>>>(pooled, Wc, bc, out, HID, C);
}

// Round 6
// 1012.453 us; speedup vs baseline: 1.0637x; 1.0366x over previous
//
#include <hip/hip_runtime.h>
#include <hip/hip_bf16.h>

// ---------------------------------------------------------------------------
// TAGConv (K=2) x2 + segment-max pool + linear head. bf16 intermediates,
// fp32 accumulate, int8 row-quantized gathers for ALL props. Layer-2
// commuted: z2@W2 = X1@W2a + P(X1@W2b + P(X1@W2c)). CSR via counting sort.
// Round 15: R5 exposed the GEMMs: 117us each (x5 = 56% of total), with
// MfmaUtil 4.3% / VALU 11% / HBM 11% / occ 17% -- pure latency
// serialization on the per-K-step vmcnt(0)-before-barrier drain (8 drains
// per block). Fix: K-resident phases of 128 (A 32KB + B 32KB = 64KB LDS,
// 2 blocks/CU): stage a whole phase -> ONE drain -> 4 barrier-free K-steps.
// Drains/block: 8 -> 2 (KK=256) / 12 -> 3 (KK=384). LDS read swizzle
// seg^(row&7) (8 slots = conflict-free, vs 4 before).
// ---------------------------------------------------------------------------

typedef unsigned short u16;
typedef unsigned int u32;
typedef unsigned char u8;

__device__ inline float u2f(u16 u) { return __uint_as_float(((u32)u) << 16); }
__device__ inline u16 f2u(float f) {
    __hip_bfloat16 b = __float2bfloat16(f);
    return *reinterpret_cast<u16*>(&b);
}

// ---------------------- CSR build: counting sort ---------------------------
// NPB = 128 nodes per bucket, NC = 128 edge chunks. NB = ceil(N/NPB) <= 784.

constexpr int NPB = 128, NC = 128, NBMAX = 784;

__global__ __launch_bounds__(256) void countA_kernel(
    const int* __restrict__ dst, int* __restrict__ Hmat, int E, int CS, int NB) {
    __shared__ int hist[NBMAX];
    int tid = threadIdx.x;
    for (int b = tid; b < NB; b += 256) hist[b] = 0;
    __syncthreads();
    int base = blockIdx.x * CS;
    int end = base + CS < E ? base + CS : E;
    for (int i = base + tid; i < end; i += 256) {
        int d = __builtin_nontemporal_load(dst + i);
        atomicAdd(&hist[d >> 7], 1);
    }
    __syncthreads();
    for (int b = tid; b < NB; b += 256) Hmat[b * NC + blockIdx.x] = hist[b];
}

__global__ __launch_bounds__(256) void scatterC_kernel(
    const int* __restrict__ src, const int* __restrict__ dst,
    const int* __restrict__ Omat, uint2* __restrict__ Earr,
    int E, int CS, int NB) {
    __shared__ int cur[NBMAX];
    int tid = threadIdx.x;
    int c = blockIdx.x;
    for (int b = tid; b < NB; b += 256) cur[b] = Omat[b * NC + c];
    __syncthreads();
    int base = c * CS;
    int end = base + CS < E ? base + CS : E;
    for (int i = base + tid; i < end; i += 256) {
        int d = __builtin_nontemporal_load(dst + i);
        int s = __builtin_nontemporal_load(src + i);
        int pos = atomicAdd(&cur[d >> 7], 1);
        uint2 e;
        e.x = (u32)s;
        e.y = (u32)(d & (NPB - 1));
        Earr[pos] = e;
    }
}

// One block per bucket: local deg count -> rowptr/normv, then colidx scatter.
__global__ __launch_bounds__(256) void fineD_kernel(
    const uint2* __restrict__ Earr, const int* __restrict__ Omat,
    int* __restrict__ colidx, int* __restrict__ rowptr,
    float* __restrict__ normv, int N, int E, int NB) {
    __shared__ int cnt[NPB];
    __shared__ int scn[NPB];
    __shared__ int cur2[NPB];
    int tid = threadIdx.x;
    int b = blockIdx.x;
    int base = Omat[b * NC];
    int end = Omat[(b + 1) * NC];   // Omat[NB*NC] = E (scan tail)
    if (tid < NPB) cnt[tid] = 0;
    __syncthreads();
    for (int i = base + tid; i < end; i += 256)
        atomicAdd(&cnt[Earr[i].y], 1);
    __syncthreads();
    if (tid < NPB) scn[tid] = cnt[tid];
    __syncthreads();
    for (int off = 1; off < NPB; off <<= 1) {
        int v = (tid < NPB && tid >= off) ? scn[tid - off] : 0;
        __syncthreads();
        if (tid < NPB) scn[tid] += v;
        __syncthreads();
    }
    int node0 = b * NPB;
    if (tid < NPB) {
        int excl = scn[tid] - cnt[tid];
        cur2[tid] = base + excl;
        int node = node0 + tid;
        if (node < N) {
            rowptr[node] = base + excl;
            int d = cnt[tid];
            float fd = d < 1 ? 1.0f : (float)d;
            normv[node] = rsqrtf(fd);
        }
    }
    if (b == 0 && tid == 0) rowptr[N] = E;
    __syncthreads();
    for (int i = base + tid; i < end; i += 256) {
        uint2 e = Earr[i];
        int pos = atomicAdd(&cur2[e.y], 1);
        colidx[pos] = (int)e.x;
    }
}

// Multi-block scan.
__global__ void scan1_kernel(const int* __restrict__ in, int* __restrict__ outp,
                             int* __restrict__ bsum, int n) {
    __shared__ int sd[1024];
    int t = threadIdx.x;
    int i = blockIdx.x * 1024 + t;
    int v = (i < n) ? in[i] : 0;
    sd[t] = v;
    __syncthreads();
    for (int off = 1; off < 1024; off <<= 1) {
        int x = (t >= off) ? sd[t - off] : 0;
        __syncthreads();
        sd[t] += x;
        __syncthreads();
    }
    if (i < n) outp[i] = sd[t] - v;
    if (t == 1023) bsum[blockIdx.x] = sd[t];
}

__global__ void scan2_kernel(int* __restrict__ bsum, int nb) {
    __shared__ int sd[1024];
    int t = threadIdx.x;
    int v = (t < nb) ? bsum[t] : 0;
    sd[t] = v;
    __syncthreads();
    for (int off = 1; off < 1024; off <<= 1) {
        int x = (t >= off) ? sd[t - off] : 0;
        __syncthreads();
        sd[t] += x;
        __syncthreads();
    }
    if (t < nb) bsum[t] = sd[t] - v;
}

__global__ void scan3_kernel(int* __restrict__ outp, const int* __restrict__ bsum,
                             int n, int E) {
    int i = blockIdx.x * blockDim.x + threadIdx.x;
    if (i < n) outp[i] += bsum[i >> 10];
    if (i == 0) outp[n] = E;
}

// ------------------------------ small structs ------------------------------

struct alignas(4) U2 { u16 v[2]; };
struct alignas(8) U4 { u16 v[4]; };
struct alignas(16) U8 { u16 v[8]; };

// --------------- fused cast+quant of h (fp32 -> bf16 + biased u8) ----------
// One 64-lane group per row (128 feats): lane holds 2 floats.

__global__ __launch_bounds__(256) void castquant_f32_128(
    const float* __restrict__ h, u16* __restrict__ cat, int ldcat,
    const float* __restrict__ normv,
    u8* __restrict__ q, float* __restrict__ m, int N) {
    int row = blockIdx.x * 4 + (threadIdx.x >> 6);
    if (row >= N) return;
    int lane = threadIdx.x & 63;
    float2 f = *(const float2*)(h + (size_t)row * 128 + lane * 2);
    U2 o;
    o.v[0] = f2u(f.x);
    o.v[1] = f2u(f.y);
    *(U2*)(cat + (size_t)row * ldcat + lane * 2) = o;
    float mx = fmaxf(fabsf(f.x), fabsf(f.y));
    #pragma unroll
    for (int off = 32; off > 0; off >>= 1)
        mx = fmaxf(mx, __shfl_xor(mx, off, 64));
    float inv = mx > 0.f ? 127.f / mx : 0.f;
    u32 q0 = (u32)((int)rintf(f.x * inv) + 128);
    u32 q1 = (u32)((int)rintf(f.y * inv) + 128);
    *(unsigned short*)(q + (size_t)row * 128 + lane * 2) =
        (unsigned short)(q0 | (q1 << 8));
    if (lane == 0) m[row] = normv[row] * (mx * (1.f / 127.f));
}

// ----------------- quant bf16[256] -> biased u8 (after GEMM) ---------------

__global__ __launch_bounds__(256) void quant_bf16_256(
    const u16* __restrict__ x, const float* __restrict__ normv,
    u8* __restrict__ q, float* __restrict__ m, int N) {
    int row = blockIdx.x * 4 + (threadIdx.x >> 6);
    if (row >= N) return;
    int lane = threadIdx.x & 63;
    U4 v = *(const U4*)(x + (size_t)row * 256 + lane * 4);
    float f[4];
    #pragma unroll
    for (int i = 0; i < 4; ++i) f[i] = u2f(v.v[i]);
    float mx = fmaxf(fmaxf(fabsf(f[0]), fabsf(f[1])),
                     fmaxf(fabsf(f[2]), fabsf(f[3])));
    #pragma unroll
    for (int off = 32; off > 0; off >>= 1)
        mx = fmaxf(mx, __shfl_xor(mx, off, 64));
    float inv = mx > 0.f ? 127.f / mx : 0.f;
    u32 b0 = (u32)((int)rintf(f[0] * inv) + 128);
    u32 b1 = (u32)((int)rintf(f[1] * inv) + 128);
    u32 b2 = (u32)((int)rintf(f[2] * inv) + 128);
    u32 b3 = (u32)((int)rintf(f[3] * inv) + 128);
    *(u32*)(q + (size_t)row * 256 + lane * 4) =
        b0 | (b1 << 8) | (b2 << 16) | (b3 << 24);
    if (lane == 0) m[row] = normv[row] * (mx * (1.f / 127.f));
}

// ------------------------- int8 row-quantized prop -------------------------
// BPL = bytes (features) per lane; D = 32*BPL. 64-lane group per dst node,
// split into two 32-lane halves, each half processes alternate edges.
// q stored biased (+128): acc = sum nm*qb - 128*sum nm  == sum nm*q.
// Main loop: full 16-edge groups, no per-edge masking (bounds are
// wave-uniform), colidx prefetched one group ahead. Tail: one masked
// clamped group. QOUT: fused re-quant of output row.

template <int BPL, int QOUT>
__global__ __launch_bounds__(256, 2) void prop_q8_kernel(
    const u8* __restrict__ qin, const float* __restrict__ m,
    u16* __restrict__ out, int ldout,
    const int* __restrict__ rowptr, const int* __restrict__ colidx,
    const float* __restrict__ normv, int N,
    u8* __restrict__ qout, float* __restrict__ mout) {
    constexpr int D = 32 * BPL;
    constexpr int NW = BPL / 4;            // u32 words per lane
    constexpr int UE = 8;                  // edges per half per group (16/group)
    int node = blockIdx.x * 4 + (threadIdx.x >> 6);
    if (node >= N) return;
    const int lane = threadIdx.x & 63;
    const int half = lane >> 5;
    const int l32 = lane & 31;
    const u32 laneoff = (u32)l32 * BPL;
    int s = rowptr[node], e = rowptr[node + 1];
    float acc[BPL];
    #pragma unroll
    for (int q = 0; q < BPL; ++q) acc[q] = 0.f;
    float msum = 0.f;
    const int nfull = (e - s) >> 4;        // full groups of 16 edges
    int p = s;
    if (nfull > 0) {
        int c[UE];
        #pragma unroll
        for (int u = 0; u < UE; ++u) c[u] = colidx[s + 2 * u + half];
        for (int g = 0; g < nfull; ++g) {
            u32 w[UE][NW];
            #pragma unroll
            for (int u = 0; u < UE; ++u) {
                u32 off = (u32)c[u] * D + laneoff;
                if (BPL == 8) {
                    uint2 gg = *(const uint2*)(qin + off);
                    w[u][0] = gg.x; w[u][1] = gg.y;
                } else {
                    w[u][0] = *(const u32*)(qin + off);
                }
            }
            float nm[UE];
            #pragma unroll
            for (int u = 0; u < UE; ++u) nm[u] = m[c[u]];
            // prefetch next group's colidx (wave-uniform branch)
            if (g + 1 < nfull) {
                int pn = s + (g + 1) * 16;
                #pragma unroll
                for (int u = 0; u < UE; ++u) c[u] = colidx[pn + 2 * u + half];
            }
            #pragma unroll
            for (int u = 0; u < UE; ++u) {
                msum += nm[u];
                #pragma unroll
                for (int t = 0; t < NW; ++t) {
                    u32 ww = w[u][t];
                    acc[4 * t + 0] += nm[u] * (float)(ww & 0xffu);
                    acc[4 * t + 1] += nm[u] * (float)((ww >> 8) & 0xffu);
                    acc[4 * t + 2] += nm[u] * (float)((ww >> 16) & 0xffu);
                    acc[4 * t + 3] += nm[u] * (float)(ww >> 24);
                }
            }
        }
        p = s + nfull * 16;
    }
    if (p < e) {
        // single masked clamped group for the tail (<16 edges)
        const int el = e - 1;
        int c[UE];
        #pragma unroll
        for (int u = 0; u < UE; ++u) {
            int idx = p + 2 * u + half;
            c[u] = colidx[idx < e ? idx : el];
        }
        u32 w[UE][NW];
        #pragma unroll
        for (int u = 0; u < UE; ++u) {
            u32 off = (u32)c[u] * D + laneoff;
            if (BPL == 8) {
                uint2 gg = *(const uint2*)(qin + off);
                w[u][0] = gg.x; w[u][1] = gg.y;
            } else {
                w[u][0] = *(const u32*)(qin + off);
            }
        }
        float nm[UE];
        #pragma unroll
        for (int u = 0; u < UE; ++u) {
            int idx = p + 2 * u + half;
            float mm = m[c[u]];
            nm[u] = idx < e ? mm : 0.f;
        }
        #pragma unroll
        for (int u = 0; u < UE; ++u) {
            msum += nm[u];
            #pragma unroll
            for (int t = 0; t < NW; ++t) {
                u32 ww = w[u][t];
                acc[4 * t + 0] += nm[u] * (float)(ww & 0xffu);
                acc[4 * t + 1] += nm[u] * (float)((ww >> 8) & 0xffu);
                acc[4 * t + 2] += nm[u] * (float)((ww >> 16) & 0xffu);
                acc[4 * t + 3] += nm[u] * (float)(ww >> 24);
            }
        }
    }
    // combine halves + bias correction + dst norm
    #pragma unroll
    for (int q = 0; q < BPL; ++q) acc[q] += __shfl_xor(acc[q], 32, 64);
    msum += __shfl_xor(msum, 32, 64);
    float nn = normv[node];
    #pragma unroll
    for (int q = 0; q < BPL; ++q) acc[q] = nn * (acc[q] - 128.f * msum);
    if (half == 0) {
        if (BPL == 8) {
            U8 o;
            #pragma unroll
            for (int q = 0; q < 8; ++q) o.v[q] = f2u(acc[q]);
            *(U8*)(out + (size_t)node * ldout + l32 * 8) = o;
        } else {
            U4 o;
            #pragma unroll
            for (int q = 0; q < 4; ++q) o.v[q] = f2u(acc[q]);
            *(U4*)(out + (size_t)node * ldout + l32 * 4) = o;
        }
    }
    if (QOUT) {
        float mx = 0.f;
        #pragma unroll
        for (int q = 0; q < BPL; ++q) mx = fmaxf(mx, fabsf(acc[q]));
        #pragma unroll
        for (int off = 16; off > 0; off >>= 1)
            mx = fmaxf(mx, __shfl_xor(mx, off, 64));
        float inv = mx > 0.f ? 127.f / mx : 0.f;
        if (half == 0) {
            u32 b[BPL > 4 ? 8 : 4];
            #pragma unroll
            for (int q = 0; q < BPL; ++q)
                b[q] = (u32)((int)rintf(acc[q] * inv) + 128);
            if (BPL == 8) {
                uint2 g;
                g.x = b[0] | (b[1] << 8) | (b[2] << 16) | (b[3] << 24);
                g.y = b[4] | (b[5] << 8) | (b[6] << 16) | (b[7] << 24);
                *(uint2*)(qout + (size_t)node * D + l32 * 8) = g;
            } else {
                *(u32*)(qout + (size_t)node * D + l32 * 4) =
                    b[0] | (b[1] << 8) | (b[2] << 16) | (b[3] << 24);
            }
            if (lane == 0) mout[node] = nn * (mx * (1.f / 127.f));
        }
    }
}

// ------------------------------- MFMA GEMM ---------------------------------
// Cout[M x 256] = [relu]( A(bf16,[Mpad x lda]) @ Bt^T [+Cadd] [+bias] ) -> bf16
// Bt is [256 x KK] bf16 row-major. Tile 128x128, 4 waves (2x2), 64x64/wave.
// K-resident phases of KH=128: stage A[128x128]+B[128x128] (64KB LDS, 2
// blocks/CU), ONE vmcnt drain per phase, then 4 barrier-free K-steps.
// LDS layout: chunk c = row*16+segl holds k-seg (segl ^ (row&7)) -> reads
// spread 16 row-lanes over 8 16B-slots = all 32 banks (conflict-free).
// 1-D grid with bijective XCD-chunk swizzle, col-fastest decode.

typedef __attribute__((ext_vector_type(8))) short bf16x8f;
typedef __attribute__((ext_vector_type(4))) float f32x4;

__device__ inline void async16(const void* g, void* l) {
    __builtin_amdgcn_global_load_lds(
        (__attribute__((address_space(1))) void*)(g),
        (__attribute__((address_space(3))) void*)(l), 16, 0, 0);
}

constexpr int GBM = 128, GBN = 128, GBK = 32, KH = 128;

template <int KK>
__global__ __launch_bounds__(256, 2) void gemm_mfma(
    const u16* __restrict__ A, int lda,
    const u16* __restrict__ Bt,          // [256 x KK]
    const u16* __restrict__ Cadd,        // nullable, [Mpad x 256]
    const float* __restrict__ bias,      // nullable, [256]
    u16* __restrict__ Cout,              // [Mpad x 256]
    int M, int relu) {
    constexpr int NPH = KK / KH;         // 2 (KK=256) or 3 (KK=384)
    __shared__ u16 Ab[GBM * KH];         // 32 KB
    __shared__ u16 Bb[GBN * KH];         // 32 KB
    const int tid = threadIdx.x;
    const int lane = tid & 63;
    const int wave = tid >> 6;
    const int wm = wave >> 1, wn = wave & 1;
    // bijective XCD-chunk swizzle, col-fastest decode (2 col-blocks share A)
    int nwg = gridDim.x;
    int qq = nwg >> 3, rr = nwg & 7;
    int xcd = blockIdx.x & 7, wi = blockIdx.x >> 3;
    int nb = (xcd < rr ? xcd * (qq + 1) : rr * (qq + 1) + (xcd - rr) * qq) + wi;
    const int row0 = (nb >> 1) * GBM;
    const int col0 = (nb & 1) * GBN;
    const int NOUT = 256;

    f32x4 acc[4][4];
    #pragma unroll
    for (int mi = 0; mi < 4; ++mi)
        #pragma unroll
        for (int ni = 0; ni < 4; ++ni) acc[mi][ni] = (f32x4)0.f;

    const int mb = lane & 15;
    const int seg4 = lane >> 4;          // k-seg within 32-wide step (0..3)

    for (int ph = 0; ph < NPH; ++ph) {
        if (ph) __syncthreads();         // all waves done reading prev phase
        // stage A and B phase panels: 8+8 async16 per thread, one drain
        #pragma unroll
        for (int i = 0; i < 8; ++i) {
            int c = tid + i * 256;       // 2048 16B chunks
            int row = c >> 4;
            int sg = (c & 15) ^ (row & 7);
            async16(A + (size_t)(row0 + row) * lda + ph * KH + sg * 8,
                    Ab + c * 8);
        }
        #pragma unroll
        for (int i = 0; i < 8; ++i) {
            int c = tid + i * 256;
            int row = c >> 4;
            int sg = (c & 15) ^ (row & 7);
            async16(Bt + (size_t)(col0 + row) * KK + ph * KH + sg * 8,
                    Bb + c * 8);
        }
        __syncthreads();                 // single vmcnt drain per phase
        #pragma unroll
        for (int ks = 0; ks < KH / GBK; ++ks) {   // 4 barrier-free K-steps
            int j = ks * 4 + seg4;
            bf16x8f a[4], b[4];
            #pragma unroll
            for (int mi = 0; mi < 4; ++mi) {
                int r = wm * 64 + mi * 16 + mb;
                int ca = r * 16 + (j ^ (r & 7));
                a[mi] = *(const bf16x8f*)&Ab[ca * 8];
            }
            #pragma unroll
            for (int ni = 0; ni < 4; ++ni) {
                int n = wn * 64 + ni * 16 + mb;
                int cb = n * 16 + (j ^ (n & 7));
                b[ni] = *(const bf16x8f*)&Bb[cb * 8];
            }
            #pragma unroll
            for (int mi = 0; mi < 4; ++mi)
                #pragma unroll
                for (int ni = 0; ni < 4; ++ni)
                    acc[mi][ni] = __builtin_amdgcn_mfma_f32_16x16x32_bf16(
                        a[mi], b[ni], acc[mi][ni], 0, 0, 0);
        }
    }

    // epilogue: C/D layout col = lane&15, row = (lane>>4)*4 + r
    #pragma unroll
    for (int mi = 0; mi < 4; ++mi) {
        #pragma unroll
        for (int r = 0; r < 4; ++r) {
            int row = row0 + wm * 64 + mi * 16 + (lane >> 4) * 4 + r;
            if (row < M) {
                #pragma unroll
                for (int ni = 0; ni < 4; ++ni) {
                    int col = col0 + wn * 64 + ni * 16 + (lane & 15);
                    float v = acc[mi][ni][r];
                    if (Cadd) v += u2f(Cadd[(size_t)row * NOUT + col]);
                    if (bias) v += bias[col];
                    if (relu) v = fmaxf(v, 0.f);
                    Cout[(size_t)row * NOUT + col] = f2u(v);
                }
            }
        }
    }
}

// Wt[n*K + k] = bf16(W[k*Nn + n])
__global__ void transpose_cast(const float* __restrict__ W, u16* __restrict__ Wt,
                               int K, int Nn) {
    int idx = blockIdx.x * blockDim.x + threadIdx.x;
    if (idx < K * Nn) {
        int n = idx / K, k = idx % K;
        Wt[idx] = f2u(W[(size_t)k * Nn + n]);
    }
}

// ------------------------------ pool + head --------------------------------

__global__ void pool_kernel(const u16* __restrict__ x, const int* __restrict__ gid,
                            float* __restrict__ pooled, int N, int HID) {
    int t = threadIdx.x;
    int n0 = blockIdx.x * 128;
    int n1 = n0 + 128 < N ? n0 + 128 : N;
    float cur = 0.f;
    int cg = gid[n0];
    for (int n = n0; n < n1; ++n) {
        int g = gid[n];
        if (g != cg) {
            atomicMax((int*)&pooled[(size_t)cg * HID + t], __float_as_int(cur));
            cg = g;
            cur = 0.f;
        }
        float v = u2f(x[(size_t)n * HID + t]);
        cur = cur > v ? cur : v;
    }
    atomicMax((int*)&pooled[(size_t)cg * HID + t], __float_as_int(cur));
}

__global__ void head_kernel(const float* __restrict__ pooled, const float* __restrict__ Wc,
                            const float* __restrict__ bc, float* __restrict__ out,
                            int HID, int C) {
    __shared__ float row[256];
    int g = blockIdx.x;
    int t = threadIdx.x;
    if (t < HID) row[t] = pooled[(size_t)g * HID + t];
    __syncthreads();
    if (t < C) {
        float s = bc[t];
        for (int k = 0; k < HID; ++k) s += row[k] * Wc[(size_t)k * C + t];
        out[(size_t)g * C + t] = s;
    }
}

// ------------------------------- launch ------------------------------------

extern "C" void kernel_launch(void* const* d_in, const int* in_sizes, int n_in,
                              void* d_out, int out_size, void* d_ws, size_t ws_size,
                              hipStream_t stream) {
    const float* h  = (const float*)d_in[0];
    const int* src  = (const int*)d_in[1];
    const int* dst  = (const int*)d_in[2];
    const int* gid  = (const int*)d_in[3];
    const float* W1 = (const float*)d_in[4];
    const float* b1 = (const float*)d_in[5];
    const float* W2 = (const float*)d_in[6];
    const float* b2 = (const float*)d_in[7];
    const float* Wc = (const float*)d_in[8];
    const float* bc = (const float*)d_in[9];
    float* out = (float*)d_out;

    const int N   = in_sizes[3];          // 100000
    const int E   = in_sizes[1];          // 3200000
    const int IN  = in_sizes[0] / N;      // 128
    const int HID = in_sizes[5];          // 256
    const int C   = in_sizes[9];          // 10
    const int G   = out_size / C;         // 64
    const int CAT = 3 * IN;               // 384
    const int Mpad = (N + 127) & ~127;    // 100096 (multiple of GBM)
    const int NB = (N + NPB - 1) / NPB;   // 782 buckets (<= NBMAX)
    const int CS = (E + NC - 1) / NC;     // 25000 edges/chunk

    char* wp = (char*)d_ws;
    auto alloc = [&](size_t bytes) {
        char* p = wp;
        wp += (bytes + 255) & ~(size_t)255;
        return p;
    };
    float* pooled = (float*)alloc((size_t)G * HID * sizeof(float));
    float* normv  = (float*)alloc((size_t)N * sizeof(float));
    float* mv     = (float*)alloc((size_t)N * sizeof(float));
    float* mv2    = (float*)alloc((size_t)N * sizeof(float));
    int* rowptr   = (int*)alloc((size_t)(N + 1) * sizeof(int));
    int* bsum     = (int*)alloc(1024 * sizeof(int));
    int* Omat     = (int*)alloc((size_t)(NB * NC + 1) * sizeof(int));
    int* Hmat     = (int*)alloc((size_t)(NB * NC) * sizeof(int));
    int* colidx   = (int*)alloc((size_t)E * sizeof(int));
    u16* Wt1      = (u16*)alloc((size_t)CAT * HID * sizeof(u16));        // [256 x 384]
    u16* Wt2      = (u16*)alloc((size_t)3 * HID * HID * sizeof(u16));    // 3 x [256 x 256]
    u16* CAT1     = (u16*)alloc((size_t)Mpad * CAT * sizeof(u16));       // [h|Ph|P2h]
    u16* X1       = (u16*)alloc((size_t)Mpad * HID * sizeof(u16));
    u16* B2       = (u16*)alloc((size_t)Mpad * HID * sizeof(u16));
    u16* B1       = CAT1;                              // alias: CAT1 dead after GEMM1
    uint2* Earr   = (uint2*)CAT1;                      // alias: dead before cast writes
    u8* Q8L2      = (u8*)(CAT1 + (size_t)Mpad * HID);  // CAT1 tail, layer-2
    u8* Q8A       = (u8*)B2;                           // B2 dead during layer 1
    u8* Q8B       = (u8*)B2 + (size_t)Mpad * 128;      // second L1 q8 buffer

    // --- CSR build: counting sort (no global atomics) ---
    const int n2 = NB * NC;               // 100096
    countA_kernel<<<NC, 256, 0, stream>>>(dst, Hmat, E, CS, NB);
    scan1_kernel<<<(n2 + 1023) / 1024, 1024, 0, stream>>>(Hmat, Omat, bsum, n2);
    scan2_kernel<<<1, 1024, 0, stream>>>(bsum, (n2 + 1023) / 1024);
    scan3_kernel<<<(n2 + 255) / 256, 256, 0, stream>>>(Omat, bsum, n2, E);
    scatterC_kernel<<<NC, 256, 0, stream>>>(src, dst, Omat, Earr, E, CS, NB);
    fineD_kernel<<<NB, 256, 0, stream>>>(Earr, Omat, colidx, rowptr, normv, N, E, NB);

    // --- weight transpose + bf16 cast (small) ---
    transpose_cast<<<(CAT * HID + 255) / 256, 256, 0, stream>>>(W1, Wt1, CAT, HID);
    for (int s2 = 0; s2 < 3; ++s2)
        transpose_cast<<<(HID * HID + 255) / 256, 256, 0, stream>>>(
            W2 + (size_t)s2 * HID * HID, Wt2 + (size_t)s2 * HID * HID, HID, HID);

    // --- layer 1: CAT1 = [bf16(h) | P h | P^2 h]; X1 = relu(CAT1@W1+b1) ---
    int pb = (N + 3) / 4;
    castquant_f32_128<<<pb, 256, 0, stream>>>(h, CAT1, CAT, normv, Q8A, mv, N);
    prop_q8_kernel<4, 1><<<pb, 256, 0, stream>>>(Q8A, mv, CAT1 + IN, CAT,
                                                 rowptr, colidx, normv, N, Q8B, mv2);
    prop_q8_kernel<4, 0><<<pb, 256, 0, stream>>>(Q8B, mv2, CAT1 + 2 * IN, CAT,
                                                 rowptr, colidx, normv, N,
                                                 nullptr, nullptr);
    int nwg = (Mpad / GBM) * (HID / GBN);   // 782 * 2 = 1564
    gemm_mfma<384><<<nwg, 256, 0, stream>>>(CAT1, CAT, Wt1, nullptr, b1, X1, N, 1);

    // --- layer 2 (commuted): X2 = relu(X1@W2a + P(X1@W2b + P(X1@W2c)) + b2) ---
    gemm_mfma<256><<<nwg, 256, 0, stream>>>(X1, HID, Wt2 + (size_t)2 * HID * HID,
                                            nullptr, nullptr, B1, N, 0);
    quant_bf16_256<<<pb, 256, 0, stream>>>(B1, normv, Q8L2, mv, N);
    prop_q8_kernel<8, 0><<<pb, 256, 0, stream>>>(Q8L2, mv, B2, HID,
                                                 rowptr, colidx, normv, N,
                                                 nullptr, nullptr);
    gemm_mfma<256><<<nwg, 256, 0, stream>>>(X1, HID, Wt2 + (size_t)HID * HID,
                                            B2, nullptr, B1, N, 0);
    quant_bf16_256<<<pb, 256, 0, stream>>>(B1, normv, Q8L2, mv, N);
    prop_q8_kernel<8, 0><<<pb, 256, 0, stream>>>(Q8L2, mv, B2, HID,
                                                 rowptr, colidx, normv, N,
                                                 nullptr, nullptr);
    gemm_mfma<256><<<nwg, 256, 0, stream>>>(X1, HID, Wt2, B2, b2, B1, N, 1);

    // --- pool + head ---
    hipMemsetAsync(pooled, 0, (size_t)G * HID * sizeof(float), stream);
    pool_kernel<<<(N + 127) / 128, HID, 0, stream>>>(B1, gid, pooled, N, HID);
    head_kernel<<<G, HID, 0, stream>>>(pooled, Wc, bc, out, HID, C);
}